// Round 7
// baseline (63.969 us; speedup 1.0000x reference)
//
#include <hip/hip_runtime.h>

typedef float f32x4 __attribute__((ext_vector_type(4)));

#define HH 128
#define WW 192
#define HO 256
#define WO 384
#define NINST 256
#define NPX (HH*WW)          // 24576 px per image
#define OTY 32               // output rows per block
#define LTY 18               // low-res rows staged (max lcount = 18)
#define LPAD 196             // tile row pitch in floats (784B)
#define STRIPS 24            // 192/8 strips per low-res row
#define NT 512               // 8 waves
#define WS_NEED (2 * NPX * 8 * 4)   // NHWC feats copy, 1.57 MB

// ---- prep: NCHW (2,8,128,192) -> NHWC (2,128,192,8) into d_ws ----
__global__ __launch_bounds__(256) void prep_nhwc(const float* __restrict__ f,
                                                 float* __restrict__ o) {
    const int j  = blockIdx.x * 256 + threadIdx.x;   // 0..49151
    const int im = j / NPX;
    const int p  = j - im * NPX;
    const float* src = f + im * 8 * NPX + p;         // lanes -> consecutive p: coalesced
    f32x4 a, b;
    a.x = src[0*NPX]; a.y = src[1*NPX]; a.z = src[2*NPX]; a.w = src[3*NPX];
    b.x = src[4*NPX]; b.y = src[5*NPX]; b.z = src[6*NPX]; b.w = src[7*NPX];
    *(f32x4*)(o + (size_t)j*8)     = a;
    *(f32x4*)(o + (size_t)j*8 + 4) = b;
}

// ---- fused: f32 MLP from NHWC feats + bilinear upsample ----
__global__ __launch_bounds__(NT) void dynmask_fused(
    const float* __restrict__ featsT,   // (2, 128, 192, 8) NHWC
    const float* __restrict__ params,   // (256, 169)
    const float* __restrict__ locs,
    const float* __restrict__ soi,
    const int*   __restrict__ im_inds,
    const int*   __restrict__ stride_p,
    float* __restrict__ out)            // (256, 1, 256, 384)
{
    const int n   = blockIdx.y;
    const int t   = threadIdx.x;
    const int oy0 = blockIdx.x * OTY;

    __shared__ float tile[LTY][LPAD];   // 14112 B

    const float sy = 127.0f / 255.0f;
    const float sx = 191.0f / 383.0f;

    const int ly0    = (int)((float)oy0 * sy);
    int lylast       = (int)((float)(oy0 + OTY - 1) * sy) + 1;
    if (lylast > HH - 1) lylast = HH - 1;
    const int lcount = lylast - ly0 + 1;             // <= 18

    // wave-uniform -> SGPRs / s_loads
    const float* __restrict__ pw = params + n * 169;
    const int   stride  = *stride_p;
    const float inv_soi = 1.0f / soi[n];
    const float loc_x   = locs[2*n+0];
    const float loc_y   = locs[2*n+1];
    const float* fbaseT = featsT + (size_t)im_inds[n] * (NPX * 8);
    const float xstep   = -(float)stride * inv_soi;

    // ---- MLP: one 8-px strip per thread, single pass (nstrips <= 432 < 512) ----
    const int nstrips = lcount * STRIPS;
    if (t < nstrips) {
        const int r  = (unsigned)t / STRIPS;         // 0..17
        const int c0 = (t - r*STRIPS) * 8;
        const int gy = ly0 + r;                      // <= 127 by construction
        const float* base = fbaseT + ((size_t)gy * WW + c0) * 8;  // 256B contiguous strip

        const float yrel = (loc_y - (float)(gy*stride + (stride>>1))) * inv_soi;
        const float xr0  = (loc_x - (float)(c0*stride + (stride>>1))) * inv_soi;

        float byo[8];
        #pragma unroll
        for (int o = 0; o < 8; ++o)
            byo[o] = fmaf(yrel, pw[o*10+1], pw[152+o]);   // y-term hoisted

        #pragma unroll
        for (int g = 0; g < 2; ++g) {
            // 8 x float4, immediate offsets off one base pointer
            f32x4 L[8];
            #pragma unroll
            for (int k = 0; k < 8; ++k)
                L[k] = *(const f32x4*)(base + g*32 + k*4);
            // px j of this group: channels 0-3 in L[2j], 4-7 in L[2j+1]

            float xr[4];
            #pragma unroll
            for (int j = 0; j < 4; ++j)
                xr[j] = fmaf((float)(g*4+j), xstep, xr0);

            // layer 0: 10 -> 8, relu
            float h0[4][8];
            #pragma unroll
            for (int o = 0; o < 8; ++o) {
                const float wxw = pw[o*10+0];
                #pragma unroll
                for (int j = 0; j < 4; ++j) {
                    float a = fmaf(xr[j], wxw, byo[o]);
                    #pragma unroll
                    for (int c = 0; c < 4; ++c)
                        a = fmaf(L[2*j][c], pw[o*10+2+c], a);
                    #pragma unroll
                    for (int c = 0; c < 4; ++c)
                        a = fmaf(L[2*j+1][c], pw[o*10+6+c], a);
                    h0[j][o] = fmaxf(a, 0.0f);
                }
            }

            // layers 1+2 fused
            f32x4 rv;
            #pragma unroll
            for (int j = 0; j < 4; ++j) rv[j] = pw[168];
            #pragma unroll
            for (int o = 0; o < 8; ++o) {
                const float b1w = pw[160+o];
                const float w2w = pw[144+o];
                #pragma unroll
                for (int j = 0; j < 4; ++j) {
                    float a = b1w;
                    #pragma unroll
                    for (int c = 0; c < 8; ++c)
                        a = fmaf(h0[j][c], pw[80+o*8+c], a);
                    rv[j] = fmaf(fmaxf(a, 0.0f), w2w, rv[j]);
                }
            }
            *(f32x4*)&tile[r][c0 + g*4] = rv;
        }
    }

    __syncthreads();

    // ---- upsample: 3 units/thread, unit = (one column, 8 rows) ----
    // 1536 units = 384 cols x 4 row-groups; each wave sits in one row-group.
    float* obase = out + (size_t)n * (HO*WO);
    #pragma unroll
    for (int k = 0; k < 3; ++k) {
        const int u   = t + k*NT;                    // 0..1535
        const int rg  = (unsigned)u / 384u;          // 0..3 (wave-uniform)
        const int col = u - rg*384;                  // 0..383
        const int r0o = rg * 8;

        const float xsf = (float)col * sx;
        int ix0 = (int)xsf; if (ix0 > WW-2) ix0 = WW-2;
        const float wx = xsf - (float)ix0;
        const float* tcol = &tile[0][0] + ix0;

        float a, b, c, d;
        int prevIy = -999;
        float* optr = obase + (size_t)(oy0 + r0o) * WO + col;

        for (int rr = 0; rr < 8; ++rr) {
            const int   yo  = oy0 + r0o + rr;
            const float ysf = (float)yo * sy;
            int iy0 = (int)ysf; if (iy0 > HH-2) iy0 = HH-2;
            const float wy = ysf - (float)iy0;

            if (iy0 != prevIy) {                     // wave-uniform branch
                const float* p = tcol + (iy0 - ly0) * LPAD;
                if (iy0 == prevIy + 1) {
                    a = c; b = d;                    // shift reuse
                    c = p[LPAD]; d = p[LPAD+1];
                } else {
                    a = p[0];    b = p[1];
                    c = p[LPAD]; d = p[LPAD+1];
                }
                prevIy = iy0;
            }

            float va = fmaf(wy, c - a, a);
            float vb = fmaf(wy, d - b, b);
            *optr = fmaf(wx, vb - va, va);           // coalesced 4B stores
            optr += WO;
        }
    }
}

// ---- fallback (round-5 f32 kernel, OTY=16) if workspace too small ----
__global__ __launch_bounds__(256) void dynmask_fused_f32(
    const float* __restrict__ feats,
    const float* __restrict__ params,
    const float* __restrict__ locs,
    const float* __restrict__ soi,
    const int*   __restrict__ im_inds,
    const int*   __restrict__ stride_p,
    float* __restrict__ out)
{
    const int n   = blockIdx.y;
    const int t   = threadIdx.x;
    const int oy0 = blockIdx.x * 16;

    __shared__ float tile[10][LPAD];

    const float sy = 127.0f / 255.0f;
    const float sx = 191.0f / 383.0f;
    const int ly0 = (int)((float)oy0 * sy);

    const float* __restrict__ pw = params + n * 169;
    const int   stride  = *stride_p;
    const float inv_soi = 1.0f / soi[n];
    const float loc_x   = locs[2*n+0];
    const float loc_y   = locs[2*n+1];
    const float* fbase  = feats + im_inds[n] * (8*HH*WW);
    const float xstep   = -(float)stride * inv_soi;

    if (t < 10 * STRIPS) {
        const int r  = (unsigned)t / STRIPS;
        const int c0 = (t - r*STRIPS) * 8;
        int gy = ly0 + r; if (gy > HH-1) gy = HH-1;
        const float* frow = fbase + gy*WW + c0;

        const float yrel = (loc_y - (float)(gy*stride + (stride>>1))) * inv_soi;
        const float xr0  = (loc_x - (float)(c0*stride + (stride>>1))) * inv_soi;

        #pragma unroll
        for (int g = 0; g < 2; ++g) {
            f32x4 f[8];
            #pragma unroll
            for (int ch = 0; ch < 8; ++ch)
                f[ch] = *(const f32x4*)(frow + ch*(HH*WW) + g*4);

            float xr[4];
            #pragma unroll
            for (int j = 0; j < 4; ++j)
                xr[j] = fmaf((float)(g*4+j), xstep, xr0);

            float h0[4][8];
            #pragma unroll
            for (int o = 0; o < 8; ++o) {
                const float byo = fmaf(yrel, pw[o*10+1], pw[152+o]);
                const float wxw = pw[o*10+0];
                #pragma unroll
                for (int j = 0; j < 4; ++j) {
                    float a = fmaf(xr[j], wxw, byo);
                    #pragma unroll
                    for (int ch = 0; ch < 8; ++ch)
                        a = fmaf(f[ch][j], pw[o*10+2+ch], a);
                    h0[j][o] = fmaxf(a, 0.0f);
                }
            }

            f32x4 rv;
            #pragma unroll
            for (int j = 0; j < 4; ++j) rv[j] = pw[168];
            #pragma unroll
            for (int o = 0; o < 8; ++o) {
                const float b1w = pw[160+o];
                const float w2w = pw[144+o];
                #pragma unroll
                for (int j = 0; j < 4; ++j) {
                    float a = b1w;
                    #pragma unroll
                    for (int c = 0; c < 8; ++c)
                        a = fmaf(h0[j][c], pw[80+o*8+c], a);
                    rv[j] = fmaf(fmaxf(a, 0.0f), w2w, rv[j]);
                }
            }
            *(f32x4*)&tile[r][c0 + g*4] = rv;
        }
    }

    __syncthreads();

    float* obase = out + (size_t)n * (HO*WO);
    #pragma unroll
    for (int k = 0; k < 3; ++k) {
        const int u    = t + k*256;
        const int wrap = (u >= 384);
        const int col  = wrap ? u - 384 : u;
        const int r0o  = wrap ? 8 : 0;

        const float xsf = (float)col * sx;
        int ix0 = (int)xsf; if (ix0 > WW-2) ix0 = WW-2;
        const float wx = xsf - (float)ix0;
        const float* tcol = &tile[0][0] + ix0;

        float a, b, c, d;
        int prevIy = -999;
        float* optr = obase + (size_t)(oy0 + r0o) * WO + col;

        for (int rr = 0; rr < 8; ++rr) {
            const int   yo  = oy0 + r0o + rr;
            const float ysf = (float)yo * sy;
            int iy0 = (int)ysf; if (iy0 > HH-2) iy0 = HH-2;
            const float wy = ysf - (float)iy0;

            if (iy0 != prevIy) {
                const float* p = tcol + (iy0 - ly0) * LPAD;
                if (iy0 == prevIy + 1) {
                    a = c; b = d;
                    c = p[LPAD]; d = p[LPAD+1];
                } else {
                    a = p[0];    b = p[1];
                    c = p[LPAD]; d = p[LPAD+1];
                }
                prevIy = iy0;
            }

            float va = fmaf(wy, c - a, a);
            float vb = fmaf(wy, d - b, b);
            *optr = fmaf(wx, vb - va, va);
            optr += WO;
        }
    }
}

extern "C" void kernel_launch(void* const* d_in, const int* in_sizes, int n_in,
                              void* d_out, int out_size, void* d_ws, size_t ws_size,
                              hipStream_t stream) {
    const float* feats    = (const float*)d_in[0];
    const float* params   = (const float*)d_in[1];
    const float* locs     = (const float*)d_in[2];
    const float* soi      = (const float*)d_in[3];
    const int*   im_inds  = (const int*)d_in[4];
    const int*   stride_p = (const int*)d_in[6];
    float* out = (float*)d_out;

    if (ws_size >= (size_t)WS_NEED) {
        float* featsT = (float*)d_ws;
        hipLaunchKernelGGL(prep_nhwc, dim3(2*NPX/256), dim3(256), 0, stream,
                           feats, featsT);
        dim3 grid(HO / OTY, NINST);   // (8, 256) = 2048 blocks
        hipLaunchKernelGGL(dynmask_fused, grid, dim3(NT), 0, stream,
                           featsT, params, locs, soi, im_inds, stride_p, out);
    } else {
        dim3 grid(HO / 16, NINST);
        hipLaunchKernelGGL(dynmask_fused_f32, grid, dim3(256), 0, stream,
                           feats, params, locs, soi, im_inds, stride_p, out);
    }
}

// Round 8
// 62.143 us; speedup vs baseline: 1.0294x; 1.0294x over previous
//
#include <hip/hip_runtime.h>

typedef float f32x4 __attribute__((ext_vector_type(4)));

#define HH 128
#define WW 192
#define HO 256
#define WO 384
#define NINST 256
#define NPX (HH*WW)          // 24576
#define STRIPS 24            // 8-px strips per low-res row
#define OTY 16               // output rows per B-block
#define LPAD 196             // LDS tile row pitch in floats (784B)
#define WS_NEED (NINST * NPX * 4)   // 25.2 MB low-res logits

// ================= Kernel A: per-instance MLP over the full low-res grid ====
// thread = one 8-px strip; 3072 strips per instance; zero halo, no divergence.
__global__ __launch_bounds__(256) void mlp_lowres(
    const float* __restrict__ feats,    // (2, 8, 128, 192) NCHW
    const float* __restrict__ params,   // (256, 169)
    const float* __restrict__ locs,
    const float* __restrict__ soi,
    const int*   __restrict__ im_inds,
    const int*   __restrict__ stride_p,
    float* __restrict__ lowres)         // (256, 128, 192) in d_ws
{
    const int n  = blockIdx.y;
    const int s  = blockIdx.x * 256 + threadIdx.x;  // 0..3071, exact cover
    const int r  = (unsigned)s / STRIPS;            // 0..127
    const int c0 = (s - r * STRIPS) * 8;            // 0..184

    // wave-uniform -> SGPRs / s_loads
    const float* __restrict__ pw = params + n * 169;
    const int   stride  = *stride_p;
    const float inv_soi = 1.0f / soi[n];
    const float loc_x   = locs[2*n+0];
    const float loc_y   = locs[2*n+1];
    const float* fbase  = feats + im_inds[n] * (8*NPX);
    const float xstep   = -(float)stride * inv_soi;

    const float* frow = fbase + r*WW + c0;
    const float yrel  = (loc_y - (float)(r*stride + (stride>>1))) * inv_soi;
    const float xr0   = (loc_x - (float)(c0*stride + (stride>>1))) * inv_soi;

    float byo[8];
    #pragma unroll
    for (int o = 0; o < 8; ++o)
        byo[o] = fmaf(yrel, pw[o*10+1], pw[152+o]);   // y-term hoisted per strip

    float* dst = lowres + (size_t)n * NPX + r*WW + c0;

    #pragma unroll
    for (int g = 0; g < 2; ++g) {
        f32x4 f[8];
        #pragma unroll
        for (int ch = 0; ch < 8; ++ch)
            f[ch] = *(const f32x4*)(frow + ch*NPX + g*4);

        float xr[4];
        #pragma unroll
        for (int j = 0; j < 4; ++j)
            xr[j] = fmaf((float)(g*4+j), xstep, xr0);

        // layer 0: 10 -> 8, relu (weights from SGPRs)
        float h0[4][8];
        #pragma unroll
        for (int o = 0; o < 8; ++o) {
            const float wxw = pw[o*10+0];
            #pragma unroll
            for (int j = 0; j < 4; ++j) {
                float a = fmaf(xr[j], wxw, byo[o]);
                #pragma unroll
                for (int ch = 0; ch < 8; ++ch)
                    a = fmaf(f[ch][j], pw[o*10+2+ch], a);
                h0[j][o] = fmaxf(a, 0.0f);
            }
        }

        // layers 1+2 fused (h1 never materialized)
        f32x4 rv;
        #pragma unroll
        for (int j = 0; j < 4; ++j) rv[j] = pw[168];
        #pragma unroll
        for (int o = 0; o < 8; ++o) {
            const float b1w = pw[160+o];
            const float w2w = pw[144+o];
            #pragma unroll
            for (int j = 0; j < 4; ++j) {
                float a = b1w;
                #pragma unroll
                for (int c = 0; c < 8; ++c)
                    a = fmaf(h0[j][c], pw[80+o*8+c], a);
                rv[j] = fmaf(fmaxf(a, 0.0f), w2w, rv[j]);
            }
        }
        *(f32x4*)(dst + g*4) = rv;   // coalesced dwordx4 (consecutive strips)
    }
}

// ================= Kernel B: 2x bilinear upsample (align_corners) ===========
// block = (instance, 16-row band); stage 10 low-res rows to LDS, then
// column-owner upsample with row-reuse; coalesced 4B stores.
__global__ __launch_bounds__(256) void upsample2x(
    const float* __restrict__ lowres,   // (256, 128, 192)
    float* __restrict__ out)            // (256, 1, 256, 384)
{
    const int n   = blockIdx.y;
    const int t   = threadIdx.x;
    const int oy0 = blockIdx.x * OTY;

    __shared__ float tile[10][LPAD];    // 7840 B

    const float sy = 127.0f / 255.0f;
    const float sx = 191.0f / 383.0f;
    const int ly0 = (int)((float)oy0 * sy);

    // ---- stage rows [ly0 .. ly0+9] (clamped) : 480 float4 loads ----
    const float* src = lowres + (size_t)n * NPX;
    #pragma unroll
    for (int k = 0; k < 2; ++k) {
        int v = t + k*256;                  // 0..479 (v<480)
        if (v < 480) {
            int row = (unsigned)v / 48u;    // 0..9
            int c4  = v - row*48;
            int gr  = ly0 + row; if (gr > HH-1) gr = HH-1;
            *(f32x4*)&tile[row][c4*4] = *(const f32x4*)(src + gr*WW + c4*4);
        }
    }
    __syncthreads();

    // ---- upsample: 3 units/thread, unit = (one column, 8 rows) ----
    float* obase = out + (size_t)n * (HO*WO);
    #pragma unroll
    for (int k = 0; k < 3; ++k) {
        const int u    = t + k*256;         // 0..767
        const int wrap = (u >= 384);
        const int col  = wrap ? u - 384 : u;    // 0..383
        const int r0o  = wrap ? 8 : 0;

        const float xsf = (float)col * sx;
        int ix0 = (int)xsf; if (ix0 > WW-2) ix0 = WW-2;
        const float wx = xsf - (float)ix0;
        const float* tcol = &tile[0][0] + ix0;

        float a, b, c, d;
        int prevIy = -999;
        float* optr = obase + (size_t)(oy0 + r0o) * WO + col;

        for (int rr = 0; rr < 8; ++rr) {
            const int   yo  = oy0 + r0o + rr;
            const float ysf = (float)yo * sy;
            int iy0 = (int)ysf; if (iy0 > HH-2) iy0 = HH-2;
            const float wy = ysf - (float)iy0;

            if (iy0 != prevIy) {                 // wave-uniform branch
                const float* p = tcol + (iy0 - ly0) * LPAD;
                if (iy0 == prevIy + 1) {
                    a = c; b = d;                // shift reuse
                    c = p[LPAD]; d = p[LPAD+1];
                } else {
                    a = p[0];    b = p[1];
                    c = p[LPAD]; d = p[LPAD+1];
                }
                prevIy = iy0;
            }

            float va = fmaf(wy, c - a, a);
            float vb = fmaf(wy, d - b, b);
            *optr = fmaf(wx, vb - va, va);
            optr += WO;
        }
    }
}

// ================= Fallback: round-5 fused kernel (ws too small) ============
__global__ __launch_bounds__(256) void dynmask_fused_f32(
    const float* __restrict__ feats,
    const float* __restrict__ params,
    const float* __restrict__ locs,
    const float* __restrict__ soi,
    const int*   __restrict__ im_inds,
    const int*   __restrict__ stride_p,
    float* __restrict__ out)
{
    const int n   = blockIdx.y;
    const int t   = threadIdx.x;
    const int oy0 = blockIdx.x * 16;

    __shared__ float tile[10][LPAD];

    const float sy = 127.0f / 255.0f;
    const float sx = 191.0f / 383.0f;
    const int ly0 = (int)((float)oy0 * sy);

    const float* __restrict__ pw = params + n * 169;
    const int   stride  = *stride_p;
    const float inv_soi = 1.0f / soi[n];
    const float loc_x   = locs[2*n+0];
    const float loc_y   = locs[2*n+1];
    const float* fbase  = feats + im_inds[n] * (8*NPX);
    const float xstep   = -(float)stride * inv_soi;

    if (t < 10 * STRIPS) {
        const int r  = (unsigned)t / STRIPS;
        const int c0 = (t - r*STRIPS) * 8;
        int gy = ly0 + r; if (gy > HH-1) gy = HH-1;
        const float* frow = fbase + gy*WW + c0;

        const float yrel = (loc_y - (float)(gy*stride + (stride>>1))) * inv_soi;
        const float xr0  = (loc_x - (float)(c0*stride + (stride>>1))) * inv_soi;

        #pragma unroll
        for (int g = 0; g < 2; ++g) {
            f32x4 f[8];
            #pragma unroll
            for (int ch = 0; ch < 8; ++ch)
                f[ch] = *(const f32x4*)(frow + ch*NPX + g*4);

            float xr[4];
            #pragma unroll
            for (int j = 0; j < 4; ++j)
                xr[j] = fmaf((float)(g*4+j), xstep, xr0);

            float h0[4][8];
            #pragma unroll
            for (int o = 0; o < 8; ++o) {
                const float byo = fmaf(yrel, pw[o*10+1], pw[152+o]);
                const float wxw = pw[o*10+0];
                #pragma unroll
                for (int j = 0; j < 4; ++j) {
                    float a = fmaf(xr[j], wxw, byo);
                    #pragma unroll
                    for (int ch = 0; ch < 8; ++ch)
                        a = fmaf(f[ch][j], pw[o*10+2+ch], a);
                    h0[j][o] = fmaxf(a, 0.0f);
                }
            }

            f32x4 rv;
            #pragma unroll
            for (int j = 0; j < 4; ++j) rv[j] = pw[168];
            #pragma unroll
            for (int o = 0; o < 8; ++o) {
                const float b1w = pw[160+o];
                const float w2w = pw[144+o];
                #pragma unroll
                for (int j = 0; j < 4; ++j) {
                    float a = b1w;
                    #pragma unroll
                    for (int c = 0; c < 8; ++c)
                        a = fmaf(h0[j][c], pw[80+o*8+c], a);
                    rv[j] = fmaf(fmaxf(a, 0.0f), w2w, rv[j]);
                }
            }
            *(f32x4*)&tile[r][c0 + g*4] = rv;
        }
    }

    __syncthreads();

    float* obase = out + (size_t)n * (HO*WO);
    #pragma unroll
    for (int k = 0; k < 3; ++k) {
        const int u    = t + k*256;
        const int wrap = (u >= 384);
        const int col  = wrap ? u - 384 : u;
        const int r0o  = wrap ? 8 : 0;

        const float xsf = (float)col * sx;
        int ix0 = (int)xsf; if (ix0 > WW-2) ix0 = WW-2;
        const float wx = xsf - (float)ix0;
        const float* tcol = &tile[0][0] + ix0;

        float a, b, c, d;
        int prevIy = -999;
        float* optr = obase + (size_t)(oy0 + r0o) * WO + col;

        for (int rr = 0; rr < 8; ++rr) {
            const int   yo  = oy0 + r0o + rr;
            const float ysf = (float)yo * sy;
            int iy0 = (int)ysf; if (iy0 > HH-2) iy0 = HH-2;
            const float wy = ysf - (float)iy0;

            if (iy0 != prevIy) {
                const float* p = tcol + (iy0 - ly0) * LPAD;
                if (iy0 == prevIy + 1) {
                    a = c; b = d;
                    c = p[LPAD]; d = p[LPAD+1];
                } else {
                    a = p[0];    b = p[1];
                    c = p[LPAD]; d = p[LPAD+1];
                }
                prevIy = iy0;
            }

            float va = fmaf(wy, c - a, a);
            float vb = fmaf(wy, d - b, b);
            *optr = fmaf(wx, vb - va, va);
            optr += WO;
        }
    }
}

extern "C" void kernel_launch(void* const* d_in, const int* in_sizes, int n_in,
                              void* d_out, int out_size, void* d_ws, size_t ws_size,
                              hipStream_t stream) {
    const float* feats    = (const float*)d_in[0];
    const float* params   = (const float*)d_in[1];
    const float* locs     = (const float*)d_in[2];
    const float* soi      = (const float*)d_in[3];
    const int*   im_inds  = (const int*)d_in[4];
    const int*   stride_p = (const int*)d_in[6];
    float* out = (float*)d_out;

    if (ws_size >= (size_t)WS_NEED) {
        float* lowres = (float*)d_ws;
        hipLaunchKernelGGL(mlp_lowres, dim3(12, NINST), dim3(256), 0, stream,
                           feats, params, locs, soi, im_inds, stride_p, lowres);
        hipLaunchKernelGGL(upsample2x, dim3(HO/OTY, NINST), dim3(256), 0, stream,
                           lowres, out);
    } else {
        hipLaunchKernelGGL(dynmask_fused_f32, dim3(HO/16, NINST), dim3(256), 0, stream,
                           feats, params, locs, soi, im_inds, stride_p, out);
    }
}

// Round 9
// 55.238 us; speedup vs baseline: 1.1581x; 1.1250x over previous
//
#include <hip/hip_runtime.h>

typedef float f32x4 __attribute__((ext_vector_type(4)));

#define HH 128
#define WW 192
#define HO 256
#define WO 384
#define NINST 256
#define NPX (HH*WW)
#define LPAD 196        // tile row pitch in floats (784B, 16B aligned)
#define SPAN 18         // low-res rows staged per 32-out-row pair

// ---- MLP for one 8-px strip -> tile row segment ----
__device__ __forceinline__ void mlp_strip(
    const float* __restrict__ frow,   // fbase + gy*WW + c0
    const float* __restrict__ pw,     // wave-uniform params row
    float yrel, float xr0, float xstep,
    float* __restrict__ dst)          // &tile[sr][c0]
{
    float byo[8];
    #pragma unroll
    for (int o = 0; o < 8; ++o)
        byo[o] = fmaf(yrel, pw[o*10+1], pw[152+o]);   // y-term hoisted

    #pragma unroll
    for (int g = 0; g < 2; ++g) {
        f32x4 f[8];
        #pragma unroll
        for (int ch = 0; ch < 8; ++ch)
            f[ch] = *(const f32x4*)(frow + ch*NPX + g*4);

        float xr[4];
        #pragma unroll
        for (int j = 0; j < 4; ++j)
            xr[j] = fmaf((float)(g*4+j), xstep, xr0);

        // layer 0: 10 -> 8, relu (weights from SGPRs)
        float h0[4][8];
        #pragma unroll
        for (int o = 0; o < 8; ++o) {
            const float wxw = pw[o*10+0];
            #pragma unroll
            for (int j = 0; j < 4; ++j) {
                float a = fmaf(xr[j], wxw, byo[o]);
                #pragma unroll
                for (int ch = 0; ch < 8; ++ch)
                    a = fmaf(f[ch][j], pw[o*10+2+ch], a);
                h0[j][o] = fmaxf(a, 0.0f);
            }
        }

        // layers 1+2 fused
        f32x4 rv;
        #pragma unroll
        for (int j = 0; j < 4; ++j) rv[j] = pw[168];
        #pragma unroll
        for (int o = 0; o < 8; ++o) {
            const float b1w = pw[160+o];
            const float w2w = pw[144+o];
            #pragma unroll
            for (int j = 0; j < 4; ++j) {
                float a = b1w;
                #pragma unroll
                for (int c = 0; c < 8; ++c)
                    a = fmaf(h0[j][c], pw[80+o*8+c], a);
                rv[j] = fmaf(fmaxf(a, 0.0f), w2w, rv[j]);
            }
        }
        *(f32x4*)(dst + g*4) = rv;
    }
}

// ---- bilinear 2x upsample of one 16-row band from the span tile ----
__device__ __forceinline__ void upsample_band(
    const float* __restrict__ tile0,  // &tile[0][0]
    int ly00, int oy0, int t,
    float* __restrict__ obase)
{
    const float sy = 127.0f / 255.0f;
    const float sx = 191.0f / 383.0f;

    #pragma unroll
    for (int k = 0; k < 3; ++k) {
        const int u    = t + k*256;          // 0..767
        const int wrap = (u >= 384);
        const int col  = wrap ? u - 384 : u; // 0..383
        const int r0o  = wrap ? 8 : 0;

        const float xsf = (float)col * sx;
        int ix0 = (int)xsf; if (ix0 > WW-2) ix0 = WW-2;
        const float wx = xsf - (float)ix0;
        const float* tcol = tile0 + ix0;

        float a, b, c, d;
        int prevIy = -999;
        float* optr = obase + (size_t)(oy0 + r0o) * WO + col;

        for (int rr = 0; rr < 8; ++rr) {
            const int   yo  = oy0 + r0o + rr;
            const float ysf = (float)yo * sy;
            int iy0 = (int)ysf; if (iy0 > HH-2) iy0 = HH-2;
            const float wy = ysf - (float)iy0;

            if (iy0 != prevIy) {             // wave-uniform branch
                const float* p = tcol + (iy0 - ly00) * LPAD;
                if (iy0 == prevIy + 1) {
                    a = c; b = d;            // shift reuse
                    c = p[LPAD]; d = p[LPAD+1];
                } else {
                    a = p[0];    b = p[1];
                    c = p[LPAD]; d = p[LPAD+1];
                }
                prevIy = iy0;
            }

            float va = fmaf(wy, c - a, a);
            float vb = fmaf(wy, d - b, b);
            *optr = fmaf(wx, vb - va, va);   // coalesced 4B stores
            optr += WO;
        }
    }
}

// ---- fused pipelined kernel: block = (instance, 32-row band pair) ----
__global__ __launch_bounds__(256) void dynmask_pipe(
    const float* __restrict__ feats,    // (2, 8, 128, 192) NCHW
    const float* __restrict__ params,   // (256, 169)
    const float* __restrict__ locs,
    const float* __restrict__ soi,
    const int*   __restrict__ im_inds,
    const int*   __restrict__ stride_p,
    float* __restrict__ out)            // (256, 1, 256, 384)
{
    const int b    = blockIdx.x;        // 0..2047
    const int n    = b & (NINST - 1);
    const int pair = b >> 8;            // 0..7
    const int t    = threadIdx.x;
    const int oy0_0 = pair * 32;
    const int oy0_1 = oy0_0 + 16;

    __shared__ float tile[SPAN][LPAD];  // 14112 B

    const float sy = 127.0f / 255.0f;
    const int ly00 = (int)((float)oy0_0 * sy);   // span base row (<=111)

    // wave-uniform -> SGPRs / s_loads
    const float* __restrict__ pw = params + n * 169;
    const int   stride  = *stride_p;
    const float inv_soi = 1.0f / soi[n];
    const float loc_x   = locs[2*n+0];
    const float loc_y   = locs[2*n+1];
    const float* fbase  = feats + im_inds[n] * (8*NPX);
    const float xstep   = -(float)stride * inv_soi;
    float* obase = out + (size_t)n * (HO*WO);

    // ---- pass 1: span rows 0..9 (240 threads) ----
    if (t < 240) {
        const int r  = (unsigned)t / 24;          // 0..9
        const int c0 = (t - r*24) * 8;
        const int gy = ly00 + r;                  // <=120, no clamp needed
        const float yrel = (loc_y - (float)(gy*stride + (stride>>1))) * inv_soi;
        const float xr0  = (loc_x - (float)(c0*stride + (stride>>1))) * inv_soi;
        mlp_strip(fbase + gy*WW + c0, pw, yrel, xr0, xstep, &tile[r][c0]);
    }
    __syncthreads();

    // ---- UP(band0) (reads rows 0..9)  ||  pass 2: rows 10..17 (192 thr) ----
    // stores issue first and drain under the MLP compute; disjoint tile rows.
    upsample_band(&tile[0][0], ly00, oy0_0, t, obase);

    if (t < 192) {
        const int rq = (unsigned)t / 24;          // 0..7
        const int r  = 10 + rq;                   // 10..17
        const int c0 = (t - rq*24) * 8;
        int gy = ly00 + r; if (gy > HH-1) gy = HH-1;   // clamp (pair 7 only)
        const float yrel = (loc_y - (float)(gy*stride + (stride>>1))) * inv_soi;
        const float xr0  = (loc_x - (float)(c0*stride + (stride>>1))) * inv_soi;
        mlp_strip(fbase + gy*WW + c0, pw, yrel, xr0, xstep, &tile[r][c0]);
    }
    __syncthreads();

    // ---- UP(band1): reads rows (ly01-ly00) .. +9  (<=17) ----
    upsample_band(&tile[0][0], ly00, oy0_1, t, obase);
}

extern "C" void kernel_launch(void* const* d_in, const int* in_sizes, int n_in,
                              void* d_out, int out_size, void* d_ws, size_t ws_size,
                              hipStream_t stream) {
    const float* feats    = (const float*)d_in[0];
    const float* params   = (const float*)d_in[1];
    const float* locs     = (const float*)d_in[2];
    const float* soi      = (const float*)d_in[3];
    const int*   im_inds  = (const int*)d_in[4];
    // d_in[5] = fpn_levels (folded into sizes_of_interest)
    const int*   stride_p = (const int*)d_in[6];
    float* out = (float*)d_out;

    hipLaunchKernelGGL(dynmask_pipe, dim3(2048), dim3(256), 0, stream,
                       feats, params, locs, soi, im_inds, stride_p, out);
}

// Round 10
// 51.650 us; speedup vs baseline: 1.2385x; 1.0695x over previous
//
#include <hip/hip_runtime.h>

typedef float f32x4 __attribute__((ext_vector_type(4)));

#define HH 128
#define WW 192
#define HO 256
#define WO 384
#define NINST 256
#define NPX (HH*WW)
#define OTY 16          // output rows per block
#define LTY 10          // low-res rows staged
#define LPAD 196        // tile row pitch in floats (784B, 16B aligned)
#define STRIPS 24       // 192/8 strips per low-res row
#define SY (127.0f/255.0f)
#define SX (191.0f/383.0f)

__global__ __launch_bounds__(256) void dynmask_fused(
    const float* __restrict__ feats,    // (2, 8, 128, 192) NCHW
    const float* __restrict__ params,   // (256, 169)
    const float* __restrict__ locs,     // (256, 2) [x, y]
    const float* __restrict__ soi,      // (256,)
    const int*   __restrict__ im_inds,  // (256,)
    const int*   __restrict__ stride_p, // (1,)
    float* __restrict__ out)            // (256, 1, 256, 384)
{
    const int n   = blockIdx.y;
    const int t   = threadIdx.x;
    const int oy0 = blockIdx.x * OTY;

    __shared__ float tile[LTY][LPAD];   // 7840 B

    const int ly0 = (int)((float)oy0 * SY);

    // wave-uniform -> SGPRs / s_loads
    const float* __restrict__ pw = params + n * 169;
    const int   stride  = *stride_p;
    const float inv_soi = 1.0f / soi[n];
    const float loc_x   = locs[2*n+0];
    const float loc_y   = locs[2*n+1];
    const float* fbase  = feats + im_inds[n] * (8*NPX);
    const float xstep   = -(float)stride * inv_soi;

    // ---- MLP: 240 threads, one 8-px strip each (identical to round 5) ----
    if (t < LTY * STRIPS) {
        const int r  = (unsigned)t / STRIPS;          // 0..9
        const int c0 = (t - r*STRIPS) * 8;
        int gy = ly0 + r; if (gy > HH-1) gy = HH-1;   // duplicate last row, benign
        const float* frow = fbase + gy*WW + c0;

        const float yrel = (loc_y - (float)(gy*stride + (stride>>1))) * inv_soi;
        const float xr0  = (loc_x - (float)(c0*stride + (stride>>1))) * inv_soi;

        #pragma unroll
        for (int g = 0; g < 2; ++g) {
            f32x4 f[8];
            #pragma unroll
            for (int ch = 0; ch < 8; ++ch)
                f[ch] = *(const f32x4*)(frow + ch*NPX + g*4);

            float xr[4];
            #pragma unroll
            for (int j = 0; j < 4; ++j)
                xr[j] = fmaf((float)(g*4+j), xstep, xr0);

            // layer 0: 10 -> 8, relu (weights via SGPR)
            float h0[4][8];
            #pragma unroll
            for (int o = 0; o < 8; ++o) {
                const float byo = fmaf(yrel, pw[o*10+1], pw[152+o]);
                const float wxw = pw[o*10+0];
                #pragma unroll
                for (int j = 0; j < 4; ++j) {
                    float a = fmaf(xr[j], wxw, byo);
                    #pragma unroll
                    for (int ch = 0; ch < 8; ++ch)
                        a = fmaf(f[ch][j], pw[o*10+2+ch], a);
                    h0[j][o] = fmaxf(a, 0.0f);
                }
            }

            // layers 1+2 fused
            f32x4 rv;
            #pragma unroll
            for (int j = 0; j < 4; ++j) rv[j] = pw[168];
            #pragma unroll
            for (int o = 0; o < 8; ++o) {
                const float b1w = pw[160+o];
                const float w2w = pw[144+o];
                #pragma unroll
                for (int j = 0; j < 4; ++j) {
                    float a = b1w;
                    #pragma unroll
                    for (int c = 0; c < 8; ++c)
                        a = fmaf(h0[j][c], pw[80+o*8+c], a);
                    rv[j] = fmaf(fmaxf(a, 0.0f), w2w, rv[j]);
                }
            }
            *(f32x4*)&tile[r][c0 + g*4] = rv;
        }
    }

    __syncthreads();

    // ---- upsample: 3 units/thread, unit = (one column, 8 rows) ----
    // All 6 LDS row-pairs issued upfront (independent); row loop is pure
    // register math with compile-time pattern indices (no scratch, rule #20).
    float* obase = out + (size_t)n * (HO*WO);
    #pragma unroll
    for (int k = 0; k < 3; ++k) {
        const int u    = t + k*256;          // 0..767
        const int wrap = (u >= 384);         // wave-uniform (384 = 6*64)
        const int col  = wrap ? u - 384 : u; // 0..383
        const int r0o  = wrap ? 8 : 0;
        const int v0   = oy0 + r0o;          // first output row of half-band

        const float xsf = (float)col * SX;
        int ix0 = (int)xsf; if (ix0 > WW-2) ix0 = WW-2;
        const float wx = xsf - (float)ix0;

        const float ysf0 = (float)v0 * SY;
        const int   iyA  = (int)ysf0;        // never needs clamp (<=123)
        const int   base = iyA - ly0;        // 0..4
        const float f0   = ysf0 - (float)iyA;

        // 6 independent ds_read2_b32: P[m] = tile[base+m][ix0 .. ix0+1]
        const float* tc = &tile[base][ix0];
        float pa0 = tc[0],        pb0 = tc[1];
        float pa1 = tc[1*LPAD],   pb1 = tc[1*LPAD+1];
        float pa2 = tc[2*LPAD],   pb2 = tc[2*LPAD+1];
        float pa3 = tc[3*LPAD],   pb3 = tc[3*LPAD+1];
        float pa4 = tc[4*LPAD],   pb4 = tc[4*LPAD+1];
        float pa5 = tc[5*LPAD],   pb5 = tc[5*LPAD+1];

        float* optr = obase + (size_t)v0 * WO + col;

        #define EMIT_ROW(RR, MLO)                                            \
        {                                                                    \
            const float wy = fmaf((float)(RR), SY, f0) - (float)(MLO);       \
            const float va = fmaf(wy, pa##MLO##N - pa##MLO, pa##MLO);        \
            const float vb = fmaf(wy, pb##MLO##N - pb##MLO, pb##MLO);        \
            *optr = fmaf(wx, vb - va, va);                                   \
            optr += WO;                                                      \
        }
        // helper aliases so MLO##N resolves to the next pair
        #define pa0N pa1
        #define pa1N pa2
        #define pa2N pa3
        #define pa3N pa4
        #define pa4N pa5
        #define pb0N pb1
        #define pb1N pb2
        #define pb2N pb3
        #define pb3N pb4
        #define pb4N pb5

        if (v0 == 0) {
            // pattern A: m = 0,0,0,1,1,2,2,3  (only block oy0=0, r0o=0)
            EMIT_ROW(0,0) EMIT_ROW(1,0) EMIT_ROW(2,0) EMIT_ROW(3,1)
            EMIT_ROW(4,1) EMIT_ROW(5,2) EMIT_ROW(6,2) EMIT_ROW(7,3)
        } else {
            // pattern B: m = 0,1,1,2,2,3,3,4  (all other half-bands)
            EMIT_ROW(0,0) EMIT_ROW(1,1) EMIT_ROW(2,1) EMIT_ROW(3,2)
            EMIT_ROW(4,2) EMIT_ROW(5,3) EMIT_ROW(6,3) EMIT_ROW(7,4)
        }
        #undef EMIT_ROW
        #undef pa0N
        #undef pa1N
        #undef pa2N
        #undef pa3N
        #undef pa4N
        #undef pb0N
        #undef pb1N
        #undef pb2N
        #undef pb3N
        #undef pb4N
    }
}

extern "C" void kernel_launch(void* const* d_in, const int* in_sizes, int n_in,
                              void* d_out, int out_size, void* d_ws, size_t ws_size,
                              hipStream_t stream) {
    const float* feats    = (const float*)d_in[0];
    const float* params   = (const float*)d_in[1];
    const float* locs     = (const float*)d_in[2];
    const float* soi      = (const float*)d_in[3];
    const int*   im_inds  = (const int*)d_in[4];
    // d_in[5] = fpn_levels (folded into sizes_of_interest)
    const int*   stride_p = (const int*)d_in[6];
    float* out = (float*)d_out;

    dim3 grid(HO / OTY, NINST);   // (16, 256) = 4096 blocks
    dim3 block(256);
    hipLaunchKernelGGL(dynmask_fused, grid, block, 0, stream,
                       feats, params, locs, soi, im_inds, stride_p, out);
}